// Round 1
// 454.898 us; speedup vs baseline: 1.0331x; 1.0331x over previous
//
#include <hip/hip_runtime.h>

#define NFEAT 128
#define H 20
#define DH 64
#define SCAN_T 1024
#define BE 64    // edges per k_mlp block (4 waves x 16)
#define CAP 96   // slot capacity per node (deg ~ Poisson(32); P(>=96) ~ 0). ushort entries.

typedef __attribute__((ext_vector_type(8))) short short8;
typedef __attribute__((ext_vector_type(4))) float f32x4;

__device__ __forceinline__ unsigned short f2bf(float f) {
    union { float f; unsigned u; } v; v.f = f;
    unsigned r = v.u + 0x7fff + ((v.u >> 16) & 1);   // RNE
    return (unsigned short)(r >> 16);
}
__device__ __forceinline__ unsigned pk2(unsigned short a, unsigned short b) {
    return (unsigned)a | ((unsigned)b << 16);
}

// DPP 16-lane sum (within each 16-lane row): VALU pipe only.
template <int CTRL>
__device__ __forceinline__ float dpp_add(float x) {
    int y = __builtin_amdgcn_update_dpp(0, __float_as_int(x), CTRL, 0xF, 0xF, true);
    return x + __int_as_float(y);
}
__device__ __forceinline__ float sum16(float x) {
    x = dpp_add<0xB1>(x);    // quad_perm [1,0,3,2]
    x = dpp_add<0x4E>(x);    // quad_perm [2,3,0,1]
    x = dpp_add<0x124>(x);   // row_ror:4
    x = dpp_add<0x128>(x);   // row_ror:8
    return x;
}

// ---------------- prep: zero deg + pack B-fragments in MFMA lane order ----------------
__global__ __launch_bounds__(256) void k_prep(const float* __restrict__ Wmu, const float* __restrict__ Wvar,
                                              const float* __restrict__ Wd1,
                                              const float* __restrict__ bmu, const float* __restrict__ bvar,
                                              unsigned short* __restrict__ Bh, unsigned short* __restrict__ Bd1,
                                              float* __restrict__ bcat, int* __restrict__ deg, int N) {
    int t = blockIdx.x * blockDim.x + threadIdx.x;
    if (t < N) deg[t] = 0;
    if (t < 512) {
        int f = t >> 6, l = t & 63;
        int tile = f >> 1, s = f & 1;
        int col = (tile & 1) * 16 + (l & 15);
        const float* W = (tile < 2) ? Wmu : Wvar;
#pragma unroll
        for (int j = 0; j < 8; j++) {
            int k = s * 32 + (l >> 4) * 8 + j;
            float v = (k < 3 * H && col < H) ? W[k * H + col] : 0.f;
            Bh[(size_t)f * 512 + l * 8 + j] = f2bf(v);
        }
    } else if (t < 768) {
        int f = (t - 512) >> 6, l = t & 63;
        int n = f * 16 + (l & 15);
#pragma unroll
        for (int j = 0; j < 8; j++) {
            int k = (l >> 4) * 8 + j;
            float v = (k < H) ? Wd1[k * DH + n] : 0.f;
            Bd1[(size_t)f * 512 + l * 8 + j] = f2bf(v);
        }
    } else if (t < 808) {
        int c = t - 768;
        bcat[c] = (c < H) ? bmu[c] : bvar[c - H];   // [bmu(20) | bvar(20)]
    }
}

// ---------------- slot path: fused degree + bucket (one atomic pass) ----------------
// Slot entries are ushort (N < 65536) and the store is a NORMAL store (not NT):
// a node's ~32 entries span one 64B line, per-XCD hot footprint ~3.2MB < 4MiB L2,
// so same-line stores combine in L2 instead of costing one full HBM line each.
__global__ __launch_bounds__(256) void k_bucket_slots(const int* __restrict__ rows, const int* __restrict__ cols,
                                                      int* __restrict__ deg, unsigned short* __restrict__ slots, int E) {
    int e = blockIdx.x * blockDim.x + threadIdx.x;
    if (e >= E) return;
    int c = __builtin_nontemporal_load(cols + e);
    int r = __builtin_nontemporal_load(rows + e);
    int pos = atomicAdd(&deg[c], 1);
    if (pos < CAP) slots[(size_t)c * CAP + pos] = (unsigned short)r;
}

// ---------------- CSR fallback path ----------------
__global__ __launch_bounds__(256) void k_deg(const int* __restrict__ cols, int* __restrict__ deg, int E) {
    int t = blockIdx.x * blockDim.x + threadIdx.x;
    if (t < E) atomicAdd(&deg[cols[t]], 1);
}

__global__ __launch_bounds__(SCAN_T) void k_scan(const int* __restrict__ deg, int* __restrict__ offsets,
                                                 int* __restrict__ cursor, int N) {
    __shared__ int sums[SCAN_T];
    int t = threadIdx.x;
    int chunk = (N + SCAN_T - 1) / SCAN_T;
    int beg = t * chunk;
    int end = min(beg + chunk, N);
    int s = 0;
    for (int i = beg; i < end; i++) s += deg[i];
    sums[t] = s;
    __syncthreads();
    for (int off = 1; off < SCAN_T; off <<= 1) {
        int v = (t >= off) ? sums[t - off] : 0;
        __syncthreads();
        sums[t] += v;
        __syncthreads();
    }
    int run = (t == 0) ? 0 : sums[t - 1];
    for (int i = beg; i < end; i++) {
        offsets[i] = run;
        cursor[i] = run;
        run += deg[i];
    }
    if (t == SCAN_T - 1) offsets[N] = sums[SCAN_T - 1];
}

__global__ __launch_bounds__(256) void k_bucket_csr(const int* __restrict__ rows, const int* __restrict__ cols,
                                                    int* __restrict__ cursor, int* __restrict__ srcs, int E) {
    int e = blockIdx.x * blockDim.x + threadIdx.x;
    if (e >= E) return;
    int pos = atomicAdd(&cursor[cols[e]], 1);
    srcs[pos] = rows[e];
}

// ---------------- xs = (x @ W_gc) * rsqrt(deg+1) ----------------
__global__ __launch_bounds__(256) void k_xw_xs(const float* __restrict__ x, const float* __restrict__ Wgc,
                                               const int* __restrict__ deg,
                                               float* __restrict__ xs, int N) {
    __shared__ float Ws[NFEAT * H];
    for (int i = threadIdx.x; i < NFEAT * H; i += blockDim.x) Ws[i] = Wgc[i];
    __syncthreads();
    int n = blockIdx.x * blockDim.x + threadIdx.x;
    if (n >= N) return;
    float acc[H];
#pragma unroll
    for (int j = 0; j < H; j++) acc[j] = 0.f;
    const float4* x4 = (const float4*)(x + (size_t)n * NFEAT);
#pragma unroll 4
    for (int k4 = 0; k4 < NFEAT / 4; k4++) {
        float4 xv = x4[k4];
#pragma unroll
        for (int s = 0; s < 4; s++) {
            float xk = (s == 0) ? xv.x : (s == 1) ? xv.y : (s == 2) ? xv.z : xv.w;
            const float4* wrow = (const float4*)(Ws + (k4 * 4 + s) * H);
#pragma unroll
            for (int q = 0; q < 5; q++) {
                float4 w = wrow[q];
                acc[q * 4 + 0] += xk * w.x;
                acc[q * 4 + 1] += xk * w.y;
                acc[q * 4 + 2] += xk * w.z;
                acc[q * 4 + 3] += xk * w.w;
            }
        }
    }
    float di = rsqrtf((float)(deg[n] + 1));
    float4* o = (float4*)(xs + (size_t)n * H);
#pragma unroll
    for (int q = 0; q < 5; q++)
        o[q] = make_float4(acc[q * 4 + 0] * di, acc[q * 4 + 1] * di, acc[q * 4 + 2] * di, acc[q * 4 + 3] * di);
}

// ---------------- gather (neighbor-parallel): 16 lanes per node, DPP reduce ----------------
template <typename IT>
__device__ __forceinline__ void gather_core16(const float* __restrict__ xs, const IT* __restrict__ idx,
                                              int beg, int end, int n, int sl, int degn,
                                              const float* __restrict__ bgc, unsigned short* __restrict__ x1b) {
    float acc[H];
    if (sl == 0) {   // self-loop term counted once
        const float4* self = (const float4*)(xs + (size_t)n * H);
#pragma unroll
        for (int q = 0; q < 5; q++) {
            float4 v = self[q];
            acc[q * 4 + 0] = v.x; acc[q * 4 + 1] = v.y; acc[q * 4 + 2] = v.z; acc[q * 4 + 3] = v.w;
        }
    } else {
#pragma unroll
        for (int j = 0; j < H; j++) acc[j] = 0.f;
    }
#pragma unroll 2
    for (int i = beg + sl; i < end; i += 16) {
        int r = (int)__builtin_nontemporal_load(idx + i);   // touch-once: keep xs L2-resident
        const float4* p = (const float4*)(xs + (size_t)r * H);
#pragma unroll
        for (int q = 0; q < 5; q++) {
            float4 v = p[q];
            acc[q * 4 + 0] += v.x; acc[q * 4 + 1] += v.y; acc[q * 4 + 2] += v.z; acc[q * 4 + 3] += v.w;
        }
    }
#pragma unroll
    for (int j = 0; j < H; j++) acc[j] = sum16(acc[j]);
    if (sl == 0) {
        float di = rsqrtf((float)(degn + 1));
        unsigned o[10];
#pragma unroll
        for (int j = 0; j < 10; j++) {
            float v0 = fmaxf(di * acc[2 * j] + bgc[2 * j], 0.f);
            float v1 = fmaxf(di * acc[2 * j + 1] + bgc[2 * j + 1], 0.f);
            o[j] = pk2(f2bf(v0), f2bf(v1));
        }
        unsigned* dst = (unsigned*)(x1b + (size_t)n * H);
        *(uint4*)dst = make_uint4(o[0], o[1], o[2], o[3]);
        *(uint4*)(dst + 4) = make_uint4(o[4], o[5], o[6], o[7]);
        *(uint2*)(dst + 8) = make_uint2(o[8], o[9]);
    }
}

__global__ __launch_bounds__(256) void k_gather_slots(const float* __restrict__ xs, const unsigned short* __restrict__ slots,
                                                      const int* __restrict__ deg, const float* __restrict__ bgc,
                                                      unsigned short* __restrict__ x1b, int N) {
    int wave = (blockIdx.x * 256 + threadIdx.x) >> 6;
    int lane = threadIdx.x & 63;
    int n = wave * 4 + (lane >> 4);
    if (n >= N) return;
    int dg = deg[n];
    int d = min(dg, CAP);
    gather_core16(xs, slots + (size_t)n * CAP, 0, d, n, lane & 15, dg, bgc, x1b);
}

__global__ __launch_bounds__(256) void k_gather_csr(const float* __restrict__ xs, const int* __restrict__ srcs,
                                                    const int* __restrict__ offsets, const int* __restrict__ deg,
                                                    const float* __restrict__ bgc,
                                                    unsigned short* __restrict__ x1b, int N) {
    int wave = (blockIdx.x * 256 + threadIdx.x) >> 6;
    int lane = threadIdx.x & 63;
    int n = wave * 4 + (lane >> 4);
    if (n >= N) return;
    gather_core16(xs, srcs, offsets[n], offsets[n + 1], n, lane & 15, deg[n], bgc, x1b);
}

// ---------------- fused per-edge MLP via MFMA ----------------
// Weights read straight from global (12 KB block-invariant -> L1-resident); LDS only
// holds the two layout-transform buffers (14.8 KB) -> 8 blocks/CU occupancy.
__global__ __launch_bounds__(256, 8) void k_mlp(
    const unsigned short* __restrict__ x1b, const int* __restrict__ rows, const int* __restrict__ cols,
    const int* __restrict__ node_id, const float* __restrict__ noise_n, const float* __restrict__ noise_u,
    const unsigned short* __restrict__ Bh, const unsigned short* __restrict__ Bd1g,
    const float* __restrict__ bcat, const float* __restrict__ b_d1,
    const float* __restrict__ W_d2, const float* __restrict__ b_d2,
    float* __restrict__ out, int E) {

    __shared__ __align__(16) unsigned short x2s[BE * 72];     // 9216 B, rows 144 B (128 used)
    __shared__ __align__(16) unsigned short A2[BE * 44];      // 5632 B, rows 88 B (feats 0..31 valid)

    int tid = threadIdx.x;
    int e0 = blockIdx.x * BE;
    int l = tid & 63, w = tid >> 6;
    int m = l & 15, quad = l >> 4;
    int erow0 = w * 16 + quad * 4;

    // ---- prefetch z-phase noise early (HBM latency overlaps staging + heads MFMA) ----
    float nz0[4], nz1[4];
#pragma unroll
    for (int r4 = 0; r4 < 4; r4++) {
        int e = e0 + erow0 + r4;
        int ec = (e < E) ? e : 0;
        nz0[r4] = noise_n[(size_t)ec * H + m];
        nz1[r4] = (m < 4) ? noise_n[(size_t)ec * H + 16 + m] : 0.f;
    }

    // ---- stage x2 rows (bf16): [x1b[r] | x1b[c] | ne | 0pad], coalesced 8B per group-of-4 lanes ----
    {
        int le = tid >> 2, p = tid & 3;
        int e = e0 + le; if (e >= E) e = E - 1;
        int r = rows[e], c = cols[e];
        int nid = node_id[0];
#pragma unroll
        for (int ii = 0; ii < 4; ii++) {
            int i = p + ii * 4;                    // 8B chunk 0..15
            unsigned* dst = (unsigned*)((char*)x2s + le * 144 + i * 8);
            if (i < 15) {
                int node = (i < 5) ? r : (i < 10) ? c : nid;
                int cc = (i < 5) ? i : (i < 10) ? i - 5 : i - 10;
                uint2 v = *(const uint2*)((const char*)x1b + (size_t)node * 40 + cc * 8);
                dst[0] = v.x;
                dst[1] = v.y;
            } else {
                dst[0] = 0u; dst[1] = 0u;
            }
        }
    }
    __syncthreads();

    // ---- heads: 4 N-tiles (mu|mu_hi|lv|lv_hi) x 2 K-steps; B-frags from global/L1 ----
    f32x4 accs[4];
    {
        const char* arow = (const char*)x2s + (w * 16 + m) * 144 + quad * 16;
        short8 a0 = *(const short8*)(arow);
        short8 a1 = *(const short8*)(arow + 64);
#pragma unroll
        for (int t4 = 0; t4 < 4; t4++) {
            f32x4 acc = {0.f, 0.f, 0.f, 0.f};
            short8 b0 = *(const short8*)(Bh + (t4 * 2 + 0) * 512 + l * 8);
            short8 b1 = *(const short8*)(Bh + (t4 * 2 + 1) * 512 + l * 8);
            acc = __builtin_amdgcn_mfma_f32_16x16x32_bf16(a0, b0, acc, 0, 0, 0);
            acc = __builtin_amdgcn_mfma_f32_16x16x32_bf16(a1, b1, acc, 0, 0, 0);
            accs[t4] = acc;
        }
    }

    // ---- z = mu + exp(lv)*noise (registers) -> ds_write_b16 into A-layout A2 (stride 88) ----
    {
        float bm0 = bcat[m];
        float bv0 = bcat[20 + m];
        float bm1 = (m < 4) ? bcat[16 + m] : 0.f;
        float bv1 = (m < 4) ? bcat[36 + m] : 0.f;
#pragma unroll
        for (int r4 = 0; r4 < 4; r4++) {
            float z0 = accs[0][r4] + bm0 + expf(accs[2][r4] + bv0) * nz0[r4];
            *(unsigned short*)((char*)A2 + (erow0 + r4) * 88 + m * 2) = f2bf(z0);
            unsigned short z1v = 0;   // lanes m>=4 zero-fill feats 20..31
            if (m < 4) z1v = f2bf(accs[1][r4] + bm1 + expf(accs[3][r4] + bv1) * nz1[r4]);
            *(unsigned short*)((char*)A2 + (erow0 + r4) * 88 + (16 + m) * 2) = z1v;
        }
    }
    __syncthreads();

    // ---- decoder: h = relu(z @ Wd1 + b), sw = relu(h . wd2 + b2), log-free gumbel gate ----
    {
        short8 a2 = *(const short8*)((const char*)A2 + (w * 16 + m) * 88 + quad * 16);
        float p0 = 0.f, p1 = 0.f, p2 = 0.f, p3 = 0.f;
#pragma unroll
        for (int t4 = 0; t4 < 4; t4++) {
            f32x4 acc = {0.f, 0.f, 0.f, 0.f};
            short8 bb = *(const short8*)(Bd1g + t4 * 512 + l * 8);
            acc = __builtin_amdgcn_mfma_f32_16x16x32_bf16(a2, bb, acc, 0, 0, 0);
            int col = t4 * 16 + m;
            float bias = b_d1[col], wo = W_d2[col];
            p0 += fmaxf(acc[0] + bias, 0.f) * wo;
            p1 += fmaxf(acc[1] + bias, 0.f) * wo;
            p2 += fmaxf(acc[2] + bias, 0.f) * wo;
            p3 += fmaxf(acc[3] + bias, 0.f) * wo;
        }
        p0 = sum16(p0); p1 = sum16(p1); p2 = sum16(p2); p3 = sum16(p3);
        if (m < 4) {
            float swv = (m == 0) ? p0 : (m == 1) ? p1 : (m == 2) ? p2 : p3;
            int leo = w * 16 + quad * 4 + m;
            int e = e0 + leo;
            if (e < E) {
                float sw = fmaxf(swv + b_d2[0], 0.f);
                float u = noise_u[e];
                float ev = 0.9999f - 0.9998f * u;
                // sigmoid(log(ev/(1-ev)) + sw) == ev / (ev + (1-ev)*exp(-sw))
                float t = expf(-sw);
                out[e] = ev / (ev + (1.f - ev) * t);
            }
        }
    }
}

extern "C" void kernel_launch(void* const* d_in, const int* in_sizes, int n_in,
                              void* d_out, int out_size, void* d_ws, size_t ws_size,
                              hipStream_t stream) {
    const int N = in_sizes[0] / NFEAT;   // 50000
    const int E = in_sizes[1] / 2;       // 1600000

    const float* x       = (const float*)d_in[0];
    const int*   ei      = (const int*)d_in[1];
    const int*   rows    = ei;
    const int*   cols    = ei + E;
    const int*   node_id = (const int*)d_in[2];
    const float* noise_n = (const float*)d_in[3];
    const float* noise_u = (const float*)d_in[4];
    const float* Wgc  = (const float*)d_in[5];
    const float* bgc  = (const float*)d_in[6];
    const float* Wmu  = (const float*)d_in[7];
    const float* bmu  = (const float*)d_in[8];
    const float* Wvar = (const float*)d_in[9];
    const float* bvar = (const float*)d_in[10];
    const float* Wd1  = (const float*)d_in[11];
    const float* bd1  = (const float*)d_in[12];
    const float* Wd2  = (const float*)d_in[13];
    const float* bd2  = (const float*)d_in[14];
    float* out = (float*)d_out;

    const int B = 256;
    int gN  = (N + B - 1) / B;
    int gG  = (N + 15) / 16;            // gather: 16 nodes per block (4 waves x 4 nodes)
    int gE  = (E + B - 1) / B;
    int gM  = (E + BE - 1) / BE;

    char* ws = (char*)d_ws;
    size_t slots_b = (size_t)N * CAP * 2;   // ushort slot entries
    bool slot_path = (ws_size >= (size_t)(200000 + slots_b + 4000000 + 2000000 + 16384));

    if (slot_path) {
        int*   deg   = (int*)ws;                                     // 200,000 B
        unsigned short* slots = (unsigned short*)(ws + 200000);      //  9,600,000 B
        float* xs    = (float*)(ws + 200000 + slots_b);              //  4,000,000 B
        char*  p     = ws + 200000 + slots_b + 4000000;
        unsigned short* x1b = (unsigned short*)p;                    //  2,000,000 B
        unsigned short* Bh  = (unsigned short*)(p + 2000000);        //      8,192 B
        unsigned short* Bd1 = (unsigned short*)(p + 2008192);        //      4,096 B
        float* bcat  = (float*)(p + 2012288);                        //        160 B

        k_prep<<<gN, B, 0, stream>>>(Wmu, Wvar, Wd1, bmu, bvar, Bh, Bd1, bcat, deg, N);
        k_bucket_slots<<<gE, B, 0, stream>>>(rows, cols, deg, slots, E);
        k_xw_xs<<<gN, B, 0, stream>>>(x, Wgc, deg, xs, N);
        k_gather_slots<<<gG, B, 0, stream>>>(xs, slots, deg, bgc, x1b, N);
        k_mlp<<<gM, B, 0, stream>>>(x1b, rows, cols, node_id, noise_n, noise_u,
                                    Bh, Bd1, bcat, bd1, Wd2, bd2, out, E);
    } else {
        int*   deg     = (int*)ws;                         //   200,000 B
        int*   offsets = (int*)(ws + 200000);              //   200,016 B
        int*   cursor  = (int*)(ws + 400016);              //   200,000 B
        int*   srcs    = (int*)(ws + 600016);              // 6,400,000 B
        float* xs      = (float*)(ws + 7000016);           // 4,000,000 B
        unsigned short* x1b = (unsigned short*)(ws + 11000016);  // 2,000,000 B
        unsigned short* Bh  = (unsigned short*)(ws + 13000016);  //     8,192 B
        unsigned short* Bd1 = (unsigned short*)(ws + 13008208);  //     4,096 B
        float* bcat    = (float*)(ws + 13012304);          //       160 B

        k_prep<<<gN, B, 0, stream>>>(Wmu, Wvar, Wd1, bmu, bvar, Bh, Bd1, bcat, deg, N);
        k_deg<<<gE, B, 0, stream>>>(cols, deg, E);
        k_scan<<<1, SCAN_T, 0, stream>>>(deg, offsets, cursor, N);
        k_bucket_csr<<<gE, B, 0, stream>>>(rows, cols, cursor, srcs, E);
        k_xw_xs<<<gN, B, 0, stream>>>(x, Wgc, deg, xs, N);
        k_gather_csr<<<gG, B, 0, stream>>>(xs, srcs, offsets, deg, bgc, x1b, N);
        k_mlp<<<gM, B, 0, stream>>>(x1b, rows, cols, node_id, noise_n, noise_u,
                                    Bh, Bd1, bcat, bd1, Wd2, bd2, out, E);
    }
}

// Round 3
// 448.196 us; speedup vs baseline: 1.0485x; 1.0150x over previous
//
#include <hip/hip_runtime.h>

#define NFEAT 128
#define H 20
#define DH 64
#define SCAN_T 1024
#define BE 64     // edges per k_mlp block (4 waves x 16)
#define NB 128    // private-histogram blocks (atomic-free counting sort)
#define HW 12800  // max histogram words (supports N <= 51200 bins, 4 u8 counters/word)

typedef __attribute__((ext_vector_type(8))) short short8;
typedef __attribute__((ext_vector_type(4))) float f32x4;

__device__ __forceinline__ unsigned short f2bf(float f) {
    union { float f; unsigned u; } v; v.f = f;
    unsigned r = v.u + 0x7fff + ((v.u >> 16) & 1);   // RNE
    return (unsigned short)(r >> 16);
}
__device__ __forceinline__ unsigned pk2(unsigned short a, unsigned short b) {
    return (unsigned)a | ((unsigned)b << 16);
}

// DPP 16-lane sum (within each 16-lane row): VALU pipe only.
template <int CTRL>
__device__ __forceinline__ float dpp_add(float x) {
    int y = __builtin_amdgcn_update_dpp(0, __float_as_int(x), CTRL, 0xF, 0xF, true);
    return x + __int_as_float(y);
}
__device__ __forceinline__ float sum16(float x) {
    x = dpp_add<0xB1>(x);    // quad_perm [1,0,3,2]
    x = dpp_add<0x4E>(x);    // quad_perm [2,3,0,1]
    x = dpp_add<0x124>(x);   // row_ror:4
    x = dpp_add<0x128>(x);   // row_ror:8
    return x;
}

// ---------------- prep: zero deg + pack B-fragments in MFMA lane order ----------------
__global__ __launch_bounds__(256) void k_prep(const float* __restrict__ Wmu, const float* __restrict__ Wvar,
                                              const float* __restrict__ Wd1,
                                              const float* __restrict__ bmu, const float* __restrict__ bvar,
                                              unsigned short* __restrict__ Bh, unsigned short* __restrict__ Bd1,
                                              float* __restrict__ bcat, int* __restrict__ deg, int N) {
    int t = blockIdx.x * blockDim.x + threadIdx.x;
    if (t < N) deg[t] = 0;   // only needed by the CSR-atomic fallback path
    if (t < 512) {
        int f = t >> 6, l = t & 63;
        int tile = f >> 1, s = f & 1;
        int col = (tile & 1) * 16 + (l & 15);
        const float* W = (tile < 2) ? Wmu : Wvar;
#pragma unroll
        for (int j = 0; j < 8; j++) {
            int k = s * 32 + (l >> 4) * 8 + j;
            float v = (k < 3 * H && col < H) ? W[k * H + col] : 0.f;
            Bh[(size_t)f * 512 + l * 8 + j] = f2bf(v);
        }
    } else if (t < 768) {
        int f = (t - 512) >> 6, l = t & 63;
        int n = f * 16 + (l & 15);
#pragma unroll
        for (int j = 0; j < 8; j++) {
            int k = (l >> 4) * 8 + j;
            float v = (k < H) ? Wd1[k * DH + n] : 0.f;
            Bd1[(size_t)f * 512 + l * 8 + j] = f2bf(v);
        }
    } else if (t < 808) {
        int c = t - 768;
        bcat[c] = (c < H) ? bmu[c] : bvar[c - H];   // [bmu(20) | bvar(20)]
    }
}

// ================= atomic-free counting sort (main path) =================
// Theory: device-scope atomicAdd bypasses the per-XCD L2s (coherence) and costs one
// ~64B memory-side RMW transaction each; 1.6M of them were 92MB of WRITE_SIZE and
// ~127us. Replace with per-block-private LDS histograms (LDS atomics are CU-local),
// a small scan, and exact-position placement -> zero global atomics on the edge path.

// Per-block histogram of cols into packed u8x4 LDS counters, dumped to a private row.
__global__ __launch_bounds__(512) void k_hist(const int* __restrict__ cols,
                                              unsigned* __restrict__ hist, int E, int N) {
    __shared__ unsigned h[HW];
    int wstride = (N + 3) >> 2;
    for (int i = threadIdx.x; i < wstride; i += 512) h[i] = 0;
    __syncthreads();
    int chunk = (E + NB - 1) / NB;
    int beg = blockIdx.x * chunk, end = min(beg + chunk, E);
    for (int i = beg + threadIdx.x; i < end; i += 512) {
        int c = __builtin_nontemporal_load(cols + i);
        atomicAdd(&h[c >> 2], 1u << ((c & 3) * 8));   // per-(block,bin) count < 256 (mean 0.25)
    }
    __syncthreads();
    unsigned* dst = hist + (size_t)blockIdx.x * wstride;
    for (int i = threadIdx.x; i < wstride; i += 512) dst[i] = h[i];   // coalesced 50KB dump
}

// Per-bin totals (deg) + per-256-bin-chunk sums for the global scan.
__global__ __launch_bounds__(256) void k_sumbins(const unsigned* __restrict__ hist,
                                                 int* __restrict__ deg, int* __restrict__ chunkSum, int N) {
    __shared__ int sc[256];
    int c = blockIdx.x * 256 + threadIdx.x;
    int wstride = (N + 3) >> 2;
    int sh = (c & 3) * 8;
    int d = 0;
    if (c < N) {
#pragma unroll 4
        for (int b = 0; b < NB; b++) d += (hist[(size_t)b * wstride + (c >> 2)] >> sh) & 0xFF;
        deg[c] = d;
    }
    sc[threadIdx.x] = d;
    __syncthreads();
    for (int off = 128; off > 0; off >>= 1) {
        if (threadIdx.x < off) sc[threadIdx.x] += sc[threadIdx.x + off];
        __syncthreads();
    }
    if (threadIdx.x == 0) chunkSum[blockIdx.x] = sc[0];
}

// Exclusive scan of <=256 chunk sums (single block).
__global__ __launch_bounds__(256) void k_scansmall(const int* __restrict__ chunkSum,
                                                   int* __restrict__ chunkOff, int nb) {
    __shared__ int sc[256];
    int t = threadIdx.x;
    int v0 = (t < nb) ? chunkSum[t] : 0;
    sc[t] = v0;
    __syncthreads();
    for (int off = 1; off < 256; off <<= 1) {
        int v = (t >= off) ? sc[t - off] : 0;
        __syncthreads();
        sc[t] += v;
        __syncthreads();
    }
    if (t < nb) chunkOff[t] = sc[t] - v0;   // exclusive
}

// offsets[c] (global CSR offsets) + per-(block,bin) u8 base deltas.
__global__ __launch_bounds__(256) void k_bases(const unsigned* __restrict__ hist,
                                               const int* __restrict__ chunkOff,
                                               unsigned char* __restrict__ delta,
                                               int* __restrict__ offsets, int N, int E) {
    __shared__ int sc[256];
    int c = blockIdx.x * 256 + threadIdx.x;
    int wstride = (N + 3) >> 2;
    int sh = (c & 3) * 8;
    int d = 0;
    if (c < N) {
#pragma unroll 4
        for (int b = 0; b < NB; b++) d += (hist[(size_t)b * wstride + (c >> 2)] >> sh) & 0xFF;
    }
    sc[threadIdx.x] = d;
    __syncthreads();
    for (int off = 1; off < 256; off <<= 1) {
        int v = (threadIdx.x >= off) ? sc[threadIdx.x - off] : 0;
        __syncthreads();
        sc[threadIdx.x] += v;
        __syncthreads();
    }
    if (c < N) {
        int base = chunkOff[blockIdx.x] + sc[threadIdx.x] - d;   // global exclusive prefix
        offsets[c] = base;
        int run = 0;   // deg[c] < 256 -> fits u8
#pragma unroll 4
        for (int b = 0; b < NB; b++) {
            delta[(size_t)b * N + c] = (unsigned char)run;       // coalesced across threads
            run += (hist[(size_t)b * wstride + (c >> 2)] >> sh) & 0xFF;
        }
    }
    if (blockIdx.x == 0 && threadIdx.x == 0) offsets[N] = E;
}

// Replay chunk; rank via LDS packed-byte cursor (atomic returns old); exact placement.
__global__ __launch_bounds__(512) void k_place(const int* __restrict__ rows, const int* __restrict__ cols,
                                               const int* __restrict__ offsets,
                                               const unsigned char* __restrict__ delta,
                                               unsigned short* __restrict__ srcs, int E, int N) {
    __shared__ unsigned h[HW];
    int wstride = (N + 3) >> 2;
    for (int i = threadIdx.x; i < wstride; i += 512) h[i] = 0;
    __syncthreads();
    int chunk = (E + NB - 1) / NB;
    int beg = blockIdx.x * chunk, end = min(beg + chunk, E);
    const unsigned char* mydelta = delta + (size_t)blockIdx.x * N;
    for (int i = beg + threadIdx.x; i < end; i += 512) {
        int c = __builtin_nontemporal_load(cols + i);
        int r = __builtin_nontemporal_load(rows + i);
        int sh = (c & 3) * 8;
        unsigned old = atomicAdd(&h[c >> 2], 1u << sh);
        int rank = (old >> sh) & 0xFF;
        int pos = offsets[c] + (int)mydelta[c] + rank;
        srcs[pos] = (unsigned short)r;
    }
}

// ---------------- CSR fallback path (global atomics; used only if ws too small) ----------------
__global__ __launch_bounds__(256) void k_deg(const int* __restrict__ cols, int* __restrict__ deg, int E) {
    int t = blockIdx.x * blockDim.x + threadIdx.x;
    if (t < E) atomicAdd(&deg[cols[t]], 1);
}

__global__ __launch_bounds__(SCAN_T) void k_scan(const int* __restrict__ deg, int* __restrict__ offsets,
                                                 int* __restrict__ cursor, int N) {
    __shared__ int sums[SCAN_T];
    int t = threadIdx.x;
    int chunk = (N + SCAN_T - 1) / SCAN_T;
    int beg = t * chunk;
    int end = min(beg + chunk, N);
    int s = 0;
    for (int i = beg; i < end; i++) s += deg[i];
    sums[t] = s;
    __syncthreads();
    for (int off = 1; off < SCAN_T; off <<= 1) {
        int v = (t >= off) ? sums[t - off] : 0;
        __syncthreads();
        sums[t] += v;
        __syncthreads();
    }
    int run = (t == 0) ? 0 : sums[t - 1];
    for (int i = beg; i < end; i++) {
        offsets[i] = run;
        cursor[i] = run;
        run += deg[i];
    }
    if (t == SCAN_T - 1) offsets[N] = sums[SCAN_T - 1];
}

__global__ __launch_bounds__(256) void k_bucket_csr(const int* __restrict__ rows, const int* __restrict__ cols,
                                                    int* __restrict__ cursor, int* __restrict__ srcs, int E) {
    int e = blockIdx.x * blockDim.x + threadIdx.x;
    if (e >= E) return;
    int pos = atomicAdd(&cursor[cols[e]], 1);
    srcs[pos] = rows[e];
}

// ---------------- xs = (x @ W_gc) * rsqrt(deg+1) ----------------
__global__ __launch_bounds__(256) void k_xw_xs(const float* __restrict__ x, const float* __restrict__ Wgc,
                                               const int* __restrict__ deg,
                                               float* __restrict__ xs, int N) {
    __shared__ float Ws[NFEAT * H];
    for (int i = threadIdx.x; i < NFEAT * H; i += blockDim.x) Ws[i] = Wgc[i];
    __syncthreads();
    int n = blockIdx.x * blockDim.x + threadIdx.x;
    if (n >= N) return;
    float acc[H];
#pragma unroll
    for (int j = 0; j < H; j++) acc[j] = 0.f;
    const float4* x4 = (const float4*)(x + (size_t)n * NFEAT);
#pragma unroll 4
    for (int k4 = 0; k4 < NFEAT / 4; k4++) {
        float4 xv = x4[k4];
#pragma unroll
        for (int s = 0; s < 4; s++) {
            float xk = (s == 0) ? xv.x : (s == 1) ? xv.y : (s == 2) ? xv.z : xv.w;
            const float4* wrow = (const float4*)(Ws + (k4 * 4 + s) * H);
#pragma unroll
            for (int q = 0; q < 5; q++) {
                float4 w = wrow[q];
                acc[q * 4 + 0] += xk * w.x;
                acc[q * 4 + 1] += xk * w.y;
                acc[q * 4 + 2] += xk * w.z;
                acc[q * 4 + 3] += xk * w.w;
            }
        }
    }
    float di = rsqrtf((float)(deg[n] + 1));
    float4* o = (float4*)(xs + (size_t)n * H);
#pragma unroll
    for (int q = 0; q < 5; q++)
        o[q] = make_float4(acc[q * 4 + 0] * di, acc[q * 4 + 1] * di, acc[q * 4 + 2] * di, acc[q * 4 + 3] * di);
}

// ---------------- gather (neighbor-parallel): 16 lanes per node, DPP reduce ----------------
template <typename IT>
__device__ __forceinline__ void gather_core16(const float* __restrict__ xs, const IT* __restrict__ idx,
                                              int beg, int end, int n, int sl, int degn,
                                              const float* __restrict__ bgc, unsigned short* __restrict__ x1b) {
    float acc[H];
    if (sl == 0) {   // self-loop term counted once
        const float4* self = (const float4*)(xs + (size_t)n * H);
#pragma unroll
        for (int q = 0; q < 5; q++) {
            float4 v = self[q];
            acc[q * 4 + 0] = v.x; acc[q * 4 + 1] = v.y; acc[q * 4 + 2] = v.z; acc[q * 4 + 3] = v.w;
        }
    } else {
#pragma unroll
        for (int j = 0; j < H; j++) acc[j] = 0.f;
    }
#pragma unroll 2
    for (int i = beg + sl; i < end; i += 16) {
        int r = (int)__builtin_nontemporal_load(idx + i);   // touch-once: keep xs L2-resident
        const float4* p = (const float4*)(xs + (size_t)r * H);
#pragma unroll
        for (int q = 0; q < 5; q++) {
            float4 v = p[q];
            acc[q * 4 + 0] += v.x; acc[q * 4 + 1] += v.y; acc[q * 4 + 2] += v.z; acc[q * 4 + 3] += v.w;
        }
    }
#pragma unroll
    for (int j = 0; j < H; j++) acc[j] = sum16(acc[j]);
    if (sl == 0) {
        float di = rsqrtf((float)(degn + 1));
        unsigned o[10];
#pragma unroll
        for (int j = 0; j < 10; j++) {
            float v0 = fmaxf(di * acc[2 * j] + bgc[2 * j], 0.f);
            float v1 = fmaxf(di * acc[2 * j + 1] + bgc[2 * j + 1], 0.f);
            o[j] = pk2(f2bf(v0), f2bf(v1));
        }
        unsigned* dst = (unsigned*)(x1b + (size_t)n * H);
        *(uint4*)dst = make_uint4(o[0], o[1], o[2], o[3]);
        *(uint4*)(dst + 4) = make_uint4(o[4], o[5], o[6], o[7]);
        *(uint2*)(dst + 8) = make_uint2(o[8], o[9]);
    }
}

__global__ __launch_bounds__(256) void k_gather_csr16(const float* __restrict__ xs, const unsigned short* __restrict__ srcs,
                                                      const int* __restrict__ offsets, const int* __restrict__ deg,
                                                      const float* __restrict__ bgc,
                                                      unsigned short* __restrict__ x1b, int N) {
    int wave = (blockIdx.x * 256 + threadIdx.x) >> 6;
    int lane = threadIdx.x & 63;
    int n = wave * 4 + (lane >> 4);
    if (n >= N) return;
    gather_core16(xs, srcs, offsets[n], offsets[n + 1], n, lane & 15, deg[n], bgc, x1b);
}

__global__ __launch_bounds__(256) void k_gather_csr(const float* __restrict__ xs, const int* __restrict__ srcs,
                                                    const int* __restrict__ offsets, const int* __restrict__ deg,
                                                    const float* __restrict__ bgc,
                                                    unsigned short* __restrict__ x1b, int N) {
    int wave = (blockIdx.x * 256 + threadIdx.x) >> 6;
    int lane = threadIdx.x & 63;
    int n = wave * 4 + (lane >> 4);
    if (n >= N) return;
    gather_core16(xs, srcs, offsets[n], offsets[n + 1], n, lane & 15, deg[n], bgc, x1b);
}

// ---------------- fused per-edge MLP via MFMA ----------------
__global__ __launch_bounds__(256, 8) void k_mlp(
    const unsigned short* __restrict__ x1b, const int* __restrict__ rows, const int* __restrict__ cols,
    const int* __restrict__ node_id, const float* __restrict__ noise_n, const float* __restrict__ noise_u,
    const unsigned short* __restrict__ Bh, const unsigned short* __restrict__ Bd1g,
    const float* __restrict__ bcat, const float* __restrict__ b_d1,
    const float* __restrict__ W_d2, const float* __restrict__ b_d2,
    float* __restrict__ out, int E) {

    __shared__ __align__(16) unsigned short x2s[BE * 72];     // 9216 B, rows 144 B (128 used)
    __shared__ __align__(16) unsigned short A2[BE * 44];      // 5632 B, rows 88 B (feats 0..31 valid)

    int tid = threadIdx.x;
    int e0 = blockIdx.x * BE;
    int l = tid & 63, w = tid >> 6;
    int m = l & 15, quad = l >> 4;
    int erow0 = w * 16 + quad * 4;

    // ---- prefetch z-phase noise early (HBM latency overlaps staging + heads MFMA) ----
    float nz0[4], nz1[4];
#pragma unroll
    for (int r4 = 0; r4 < 4; r4++) {
        int e = e0 + erow0 + r4;
        int ec = (e < E) ? e : 0;
        nz0[r4] = noise_n[(size_t)ec * H + m];
        nz1[r4] = (m < 4) ? noise_n[(size_t)ec * H + 16 + m] : 0.f;
    }

    // ---- stage x2 rows (bf16): [x1b[r] | x1b[c] | ne | 0pad], coalesced 8B per group-of-4 lanes ----
    {
        int le = tid >> 2, p = tid & 3;
        int e = e0 + le; if (e >= E) e = E - 1;
        int r = rows[e], c = cols[e];
        int nid = node_id[0];
#pragma unroll
        for (int ii = 0; ii < 4; ii++) {
            int i = p + ii * 4;                    // 8B chunk 0..15
            unsigned* dst = (unsigned*)((char*)x2s + le * 144 + i * 8);
            if (i < 15) {
                int node = (i < 5) ? r : (i < 10) ? c : nid;
                int cc = (i < 5) ? i : (i < 10) ? i - 5 : i - 10;
                uint2 v = *(const uint2*)((const char*)x1b + (size_t)node * 40 + cc * 8);
                dst[0] = v.x;
                dst[1] = v.y;
            } else {
                dst[0] = 0u; dst[1] = 0u;
            }
        }
    }
    __syncthreads();

    // ---- heads: 4 N-tiles (mu|mu_hi|lv|lv_hi) x 2 K-steps; B-frags from global/L1 ----
    f32x4 accs[4];
    {
        const char* arow = (const char*)x2s + (w * 16 + m) * 144 + quad * 16;
        short8 a0 = *(const short8*)(arow);
        short8 a1 = *(const short8*)(arow + 64);
#pragma unroll
        for (int t4 = 0; t4 < 4; t4++) {
            f32x4 acc = {0.f, 0.f, 0.f, 0.f};
            short8 b0 = *(const short8*)(Bh + (t4 * 2 + 0) * 512 + l * 8);
            short8 b1 = *(const short8*)(Bh + (t4 * 2 + 1) * 512 + l * 8);
            acc = __builtin_amdgcn_mfma_f32_16x16x32_bf16(a0, b0, acc, 0, 0, 0);
            acc = __builtin_amdgcn_mfma_f32_16x16x32_bf16(a1, b1, acc, 0, 0, 0);
            accs[t4] = acc;
        }
    }

    // ---- z = mu + exp(lv)*noise (registers) -> ds_write_b16 into A-layout A2 (stride 88) ----
    {
        float bm0 = bcat[m];
        float bv0 = bcat[20 + m];
        float bm1 = (m < 4) ? bcat[16 + m] : 0.f;
        float bv1 = (m < 4) ? bcat[36 + m] : 0.f;
#pragma unroll
        for (int r4 = 0; r4 < 4; r4++) {
            float z0 = accs[0][r4] + bm0 + expf(accs[2][r4] + bv0) * nz0[r4];
            *(unsigned short*)((char*)A2 + (erow0 + r4) * 88 + m * 2) = f2bf(z0);
            unsigned short z1v = 0;   // lanes m>=4 zero-fill feats 20..31
            if (m < 4) z1v = f2bf(accs[1][r4] + bm1 + expf(accs[3][r4] + bv1) * nz1[r4]);
            *(unsigned short*)((char*)A2 + (erow0 + r4) * 88 + (16 + m) * 2) = z1v;
        }
    }
    __syncthreads();

    // ---- decoder: h = relu(z @ Wd1 + b), sw = relu(h . wd2 + b2), log-free gumbel gate ----
    {
        short8 a2 = *(const short8*)((const char*)A2 + (w * 16 + m) * 88 + quad * 16);
        float p0 = 0.f, p1 = 0.f, p2 = 0.f, p3 = 0.f;
#pragma unroll
        for (int t4 = 0; t4 < 4; t4++) {
            f32x4 acc = {0.f, 0.f, 0.f, 0.f};
            short8 bb = *(const short8*)(Bd1g + t4 * 512 + l * 8);
            acc = __builtin_amdgcn_mfma_f32_16x16x32_bf16(a2, bb, acc, 0, 0, 0);
            int col = t4 * 16 + m;
            float bias = b_d1[col], wo = W_d2[col];
            p0 += fmaxf(acc[0] + bias, 0.f) * wo;
            p1 += fmaxf(acc[1] + bias, 0.f) * wo;
            p2 += fmaxf(acc[2] + bias, 0.f) * wo;
            p3 += fmaxf(acc[3] + bias, 0.f) * wo;
        }
        p0 = sum16(p0); p1 = sum16(p1); p2 = sum16(p2); p3 = sum16(p3);
        if (m < 4) {
            float swv = (m == 0) ? p0 : (m == 1) ? p1 : (m == 2) ? p2 : p3;
            int leo = w * 16 + quad * 4 + m;
            int e = e0 + leo;
            if (e < E) {
                float sw = fmaxf(swv + b_d2[0], 0.f);
                float u = noise_u[e];
                float ev = 0.9999f - 0.9998f * u;
                // sigmoid(log(ev/(1-ev)) + sw) == ev / (ev + (1-ev)*exp(-sw))
                float t = expf(-sw);
                out[e] = ev / (ev + (1.f - ev) * t);
            }
        }
    }
}

extern "C" void kernel_launch(void* const* d_in, const int* in_sizes, int n_in,
                              void* d_out, int out_size, void* d_ws, size_t ws_size,
                              hipStream_t stream) {
    const int N = in_sizes[0] / NFEAT;   // 50000
    const int E = in_sizes[1] / 2;       // 1600000

    const float* x       = (const float*)d_in[0];
    const int*   ei      = (const int*)d_in[1];
    const int*   rows    = ei;
    const int*   cols    = ei + E;
    const int*   node_id = (const int*)d_in[2];
    const float* noise_n = (const float*)d_in[3];
    const float* noise_u = (const float*)d_in[4];
    const float* Wgc  = (const float*)d_in[5];
    const float* bgc  = (const float*)d_in[6];
    const float* Wmu  = (const float*)d_in[7];
    const float* bmu  = (const float*)d_in[8];
    const float* Wvar = (const float*)d_in[9];
    const float* bvar = (const float*)d_in[10];
    const float* Wd1  = (const float*)d_in[11];
    const float* bd1  = (const float*)d_in[12];
    const float* Wd2  = (const float*)d_in[13];
    const float* bd2  = (const float*)d_in[14];
    float* out = (float*)d_out;

    const int B = 256;
    int gN  = (N + B - 1) / B;
    int gG  = (N + 15) / 16;            // gather: 16 nodes per block (4 waves x 4 nodes)
    int gE  = (E + B - 1) / B;
    int gM  = (E + BE - 1) / BE;
    int nBins = (N + 255) / 256;        // <= 256 for N <= 65536

    char* ws = (char*)d_ws;
    // main-path layout (256B-aligned regions)
    size_t o_deg     = 0;
    size_t o_off     = o_deg  + (((size_t)N * 4 + 255) & ~255ULL);
    size_t o_csum    = o_off  + (((size_t)(N + 1) * 4 + 255) & ~255ULL);
    size_t o_coff    = o_csum + 1024;
    size_t o_hist    = o_coff + 1024;
    size_t wstride   = (size_t)((N + 3) >> 2);
    size_t o_delta   = o_hist  + ((NB * wstride * 4 + 255) & ~255ULL);
    size_t o_srcs    = o_delta + (((size_t)NB * N + 255) & ~255ULL);
    size_t o_xs      = o_srcs  + (((size_t)E * 2 + 255) & ~255ULL);
    size_t o_x1b     = o_xs    + (((size_t)N * H * 4 + 255) & ~255ULL);
    size_t o_Bh      = o_x1b   + (((size_t)N * H * 2 + 255) & ~255ULL);
    size_t o_Bd1     = o_Bh    + 8192;
    size_t o_bcat    = o_Bd1   + 4096;
    size_t need      = o_bcat  + 256;

    bool main_path = (ws_size >= need) && (N <= 4 * HW) && (N < 65536) && (nBins <= 256);

    if (main_path) {
        int*   deg     = (int*)(ws + o_deg);
        int*   offsets = (int*)(ws + o_off);
        int*   csum    = (int*)(ws + o_csum);
        int*   coff    = (int*)(ws + o_coff);
        unsigned* hist = (unsigned*)(ws + o_hist);
        unsigned char* delta = (unsigned char*)(ws + o_delta);
        unsigned short* srcs = (unsigned short*)(ws + o_srcs);
        float* xs      = (float*)(ws + o_xs);
        unsigned short* x1b  = (unsigned short*)(ws + o_x1b);
        unsigned short* Bh   = (unsigned short*)(ws + o_Bh);
        unsigned short* Bd1  = (unsigned short*)(ws + o_Bd1);
        float* bcat    = (float*)(ws + o_bcat);

        k_prep<<<gN, B, 0, stream>>>(Wmu, Wvar, Wd1, bmu, bvar, Bh, Bd1, bcat, deg, N);
        k_hist<<<NB, 512, 0, stream>>>(cols, hist, E, N);
        k_sumbins<<<nBins, B, 0, stream>>>(hist, deg, csum, N);
        k_scansmall<<<1, B, 0, stream>>>(csum, coff, nBins);
        k_bases<<<nBins, B, 0, stream>>>(hist, coff, delta, offsets, N, E);
        k_xw_xs<<<gN, B, 0, stream>>>(x, Wgc, deg, xs, N);
        k_place<<<NB, 512, 0, stream>>>(rows, cols, offsets, delta, srcs, E, N);
        k_gather_csr16<<<gG, B, 0, stream>>>(xs, srcs, offsets, deg, bgc, x1b, N);
        k_mlp<<<gM, B, 0, stream>>>(x1b, rows, cols, node_id, noise_n, noise_u,
                                    Bh, Bd1, bcat, bd1, Wd2, bd2, out, E);
    } else {
        int*   deg     = (int*)ws;                         //   200,000 B
        int*   offsets = (int*)(ws + 200000);              //   200,016 B
        int*   cursor  = (int*)(ws + 400016);              //   200,000 B
        int*   srcs    = (int*)(ws + 600016);              // 6,400,000 B
        float* xs      = (float*)(ws + 7000016);           // 4,000,000 B
        unsigned short* x1b = (unsigned short*)(ws + 11000016);  // 2,000,000 B
        unsigned short* Bh  = (unsigned short*)(ws + 13000016);  //     8,192 B
        unsigned short* Bd1 = (unsigned short*)(ws + 13008208);  //     4,096 B
        float* bcat    = (float*)(ws + 13012304);          //       160 B

        k_prep<<<gN, B, 0, stream>>>(Wmu, Wvar, Wd1, bmu, bvar, Bh, Bd1, bcat, deg, N);
        k_deg<<<gE, B, 0, stream>>>(cols, deg, E);
        k_scan<<<1, SCAN_T, 0, stream>>>(deg, offsets, cursor, N);
        k_bucket_csr<<<gE, B, 0, stream>>>(rows, cols, cursor, srcs, E);
        k_xw_xs<<<gN, B, 0, stream>>>(x, Wgc, deg, xs, N);
        k_gather_csr<<<gG, B, 0, stream>>>(xs, srcs, offsets, deg, bgc, x1b, N);
        k_mlp<<<gM, B, 0, stream>>>(x1b, rows, cols, node_id, noise_n, noise_u,
                                    Bh, Bd1, bcat, bd1, Wd2, bd2, out, E);
    }
}

// Round 4
// 430.415 us; speedup vs baseline: 1.0918x; 1.0413x over previous
//
#include <hip/hip_runtime.h>

#define NFEAT 128
#define H 20
#define DH 64
#define SCAN_T 1024
#define BE 64     // edges per k_mlp block (4 waves x 16)
#define NB 192    // private-histogram blocks (atomic-free counting sort)
#define HW 12800  // max histogram words (supports N <= 51200 bins, 4 u8 counters/word)

typedef __attribute__((ext_vector_type(8))) short short8;
typedef __attribute__((ext_vector_type(4))) float f32x4;

__device__ __forceinline__ unsigned short f2bf(float f) {
    union { float f; unsigned u; } v; v.f = f;
    unsigned r = v.u + 0x7fff + ((v.u >> 16) & 1);   // RNE
    return (unsigned short)(r >> 16);
}
__device__ __forceinline__ unsigned pk2(unsigned short a, unsigned short b) {
    return (unsigned)a | ((unsigned)b << 16);
}

// DPP 16-lane sum (within each 16-lane row): VALU pipe only. All 16 lanes get the total.
template <int CTRL>
__device__ __forceinline__ float dpp_add(float x) {
    int y = __builtin_amdgcn_update_dpp(0, __float_as_int(x), CTRL, 0xF, 0xF, true);
    return x + __int_as_float(y);
}
__device__ __forceinline__ float sum16(float x) {
    x = dpp_add<0xB1>(x);    // quad_perm [1,0,3,2]
    x = dpp_add<0x4E>(x);    // quad_perm [2,3,0,1]
    x = dpp_add<0x124>(x);   // row_ror:4
    x = dpp_add<0x128>(x);   // row_ror:8
    return x;
}

// ---------------- prep: zero deg/csum + pack B-fragments in MFMA lane order ----------------
// Head weights: rows >= 40 (node_id embedding) are ZEROED — their contribution is folded
// into the bias vector bcat2 by the gather kernel (block-invariant across all edges).
__global__ __launch_bounds__(256) void k_prep(const float* __restrict__ Wmu, const float* __restrict__ Wvar,
                                              const float* __restrict__ Wd1,
                                              unsigned short* __restrict__ Bh, unsigned short* __restrict__ Bd1,
                                              int* __restrict__ deg, int* __restrict__ csum, int N) {
    int t = blockIdx.x * blockDim.x + threadIdx.x;
    if (t < N) deg[t] = 0;   // needed by the CSR-atomic fallback path
    if (t < 256) csum[t] = 0;
    if (t < 512) {
        int f = t >> 6, l = t & 63;
        int tile = f >> 1, s = f & 1;
        int col = (tile & 1) * 16 + (l & 15);
        const float* W = (tile < 2) ? Wmu : Wvar;
#pragma unroll
        for (int j = 0; j < 8; j++) {
            int k = s * 32 + (l >> 4) * 8 + j;
            float v = (k < 2 * H && col < H) ? W[k * H + col] : 0.f;   // rows >= 40 zero (nid fold)
            Bh[(size_t)f * 512 + l * 8 + j] = f2bf(v);
        }
    } else if (t < 768) {
        int f = (t - 512) >> 6, l = t & 63;
        int n = f * 16 + (l & 15);
#pragma unroll
        for (int j = 0; j < 8; j++) {
            int k = (l >> 4) * 8 + j;
            float v = (k < H) ? Wd1[k * DH + n] : 0.f;
            Bd1[(size_t)f * 512 + l * 8 + j] = f2bf(v);
        }
    }
}

// ================= atomic-free counting sort (main path) =================
// Per-block histogram of cols into packed u8x4 LDS counters; also accumulates
// per-256-bin chunk sums (LDS-aggregated, ~NB*196 global atomics total — noise).
__global__ __launch_bounds__(512) void k_hist(const int* __restrict__ cols,
                                              unsigned* __restrict__ hist, int* __restrict__ csum,
                                              int E, int N) {
    __shared__ unsigned h[HW];
    __shared__ int cs[256];
    int wstride = (N + 3) >> 2;
    int nchunks = (N + 255) >> 8;
    for (int i = threadIdx.x; i < wstride; i += 512) h[i] = 0;
    if (threadIdx.x < 256) cs[threadIdx.x] = 0;
    __syncthreads();
    int chunk = (E + NB - 1) / NB;
    int beg = blockIdx.x * chunk, end = min(beg + chunk, E);
    for (int i = beg + threadIdx.x; i < end; i += 512) {
        int c = __builtin_nontemporal_load(cols + i);
        atomicAdd(&h[c >> 2], 1u << ((c & 3) * 8));   // per-(block,bin) count < 256
    }
    __syncthreads();
    unsigned* dst = hist + (size_t)blockIdx.x * wstride;
    for (int i = threadIdx.x; i < wstride; i += 512) {
        unsigned w = h[i];
        dst[i] = w;                                    // coalesced dump
        if (w) {
            int s = (w & 0xFF) + ((w >> 8) & 0xFF) + ((w >> 16) & 0xFF) + (w >> 24);
            atomicAdd(&cs[i >> 6], s);                 // word i covers bins 4i..4i+3 -> chunk i>>6
        }
    }
    __syncthreads();
    for (int j = threadIdx.x; j < nchunks; j += 512)
        if (cs[j]) atomicAdd(&csum[j], cs[j]);
}

// Exclusive scan of <=256 chunk sums (single block).
__global__ __launch_bounds__(256) void k_scansmall(const int* __restrict__ chunkSum,
                                                   int* __restrict__ chunkOff, int nb) {
    __shared__ int sc[256];
    int t = threadIdx.x;
    int v0 = (t < nb) ? chunkSum[t] : 0;
    sc[t] = v0;
    __syncthreads();
    for (int off = 1; off < 256; off <<= 1) {
        int v = (t >= off) ? sc[t - off] : 0;
        __syncthreads();
        sc[t] += v;
        __syncthreads();
    }
    if (t < nb) chunkOff[t] = sc[t] - v0;   // exclusive
}

// SINGLE-PASS bases: read hist once, cache per-block counts in packed registers
// (fully unrolled -> compile-time indices, no scratch), emit deg + offsets + delta.
__global__ __launch_bounds__(256) void k_bases(const unsigned* __restrict__ hist,
                                               const int* __restrict__ chunkOff,
                                               unsigned char* __restrict__ delta,
                                               int* __restrict__ offsets, int* __restrict__ deg,
                                               int N, int E) {
    __shared__ int sc[256];
    int c = blockIdx.x * 256 + threadIdx.x;
    int wstride = (N + 3) >> 2;
    int sh = (c & 3) * 8;
    bool valid = c < N;
    int cw = valid ? (c >> 2) : 0;
    unsigned cnt[NB / 4];   // NB u8 counts packed 4-per-word, compile-time indexed
    int d = 0;
#pragma unroll
    for (int b = 0; b < NB; b++) {
        unsigned w = hist[(size_t)b * wstride + cw];
        unsigned byte = (w >> sh) & 0xFF;
        if ((b & 3) == 0) cnt[b >> 2] = byte;
        else cnt[b >> 2] |= byte << ((b & 3) * 8);
        d += (int)byte;
    }
    if (!valid) d = 0;
    sc[threadIdx.x] = d;
    __syncthreads();
    for (int off = 1; off < 256; off <<= 1) {
        int v = (threadIdx.x >= off) ? sc[threadIdx.x - off] : 0;
        __syncthreads();
        sc[threadIdx.x] += v;
        __syncthreads();
    }
    if (valid) {
        int base = chunkOff[blockIdx.x] + sc[threadIdx.x] - d;   // global exclusive prefix
        offsets[c] = base;
        deg[c] = d;
        int run = 0;   // deg[c] < 256 -> fits u8
#pragma unroll
        for (int b = 0; b < NB; b++) {
            delta[(size_t)b * N + c] = (unsigned char)run;       // coalesced across threads
            run += (int)((cnt[b >> 2] >> ((b & 3) * 8)) & 0xFF);
        }
    }
    if (blockIdx.x == 0 && threadIdx.x == 0) offsets[N] = E;
}

// Replay chunk; rank via LDS packed-byte cursor (atomic returns old); exact placement.
__global__ __launch_bounds__(512) void k_place(const int* __restrict__ rows, const int* __restrict__ cols,
                                               const int* __restrict__ offsets,
                                               const unsigned char* __restrict__ delta,
                                               unsigned short* __restrict__ srcs, int E, int N) {
    __shared__ unsigned h[HW];
    int wstride = (N + 3) >> 2;
    for (int i = threadIdx.x; i < wstride; i += 512) h[i] = 0;
    __syncthreads();
    int chunk = (E + NB - 1) / NB;
    int beg = blockIdx.x * chunk, end = min(beg + chunk, E);
    const unsigned char* mydelta = delta + (size_t)blockIdx.x * N;
    for (int i = beg + threadIdx.x; i < end; i += 512) {
        int c = __builtin_nontemporal_load(cols + i);
        int r = __builtin_nontemporal_load(rows + i);
        int sh = (c & 3) * 8;
        unsigned old = atomicAdd(&h[c >> 2], 1u << sh);
        int rank = (old >> sh) & 0xFF;
        int pos = offsets[c] + (int)mydelta[c] + rank;
        srcs[pos] = (unsigned short)r;
    }
}

// ---------------- CSR fallback path (global atomics; used only if ws too small) ----------------
__global__ __launch_bounds__(256) void k_deg(const int* __restrict__ cols, int* __restrict__ deg, int E) {
    int t = blockIdx.x * blockDim.x + threadIdx.x;
    if (t < E) atomicAdd(&deg[cols[t]], 1);
}

__global__ __launch_bounds__(SCAN_T) void k_scan(const int* __restrict__ deg, int* __restrict__ offsets,
                                                 int* __restrict__ cursor, int N) {
    __shared__ int sums[SCAN_T];
    int t = threadIdx.x;
    int chunk = (N + SCAN_T - 1) / SCAN_T;
    int beg = t * chunk;
    int end = min(beg + chunk, N);
    int s = 0;
    for (int i = beg; i < end; i++) s += deg[i];
    sums[t] = s;
    __syncthreads();
    for (int off = 1; off < SCAN_T; off <<= 1) {
        int v = (t >= off) ? sums[t - off] : 0;
        __syncthreads();
        sums[t] += v;
        __syncthreads();
    }
    int run = (t == 0) ? 0 : sums[t - 1];
    for (int i = beg; i < end; i++) {
        offsets[i] = run;
        cursor[i] = run;
        run += deg[i];
    }
    if (t == SCAN_T - 1) offsets[N] = sums[SCAN_T - 1];
}

__global__ __launch_bounds__(256) void k_bucket_csr(const int* __restrict__ rows, const int* __restrict__ cols,
                                                    int* __restrict__ cursor, int* __restrict__ srcs, int E) {
    int e = blockIdx.x * blockDim.x + threadIdx.x;
    if (e >= E) return;
    int pos = atomicAdd(&cursor[cols[e]], 1);
    srcs[pos] = rows[e];
}

// ---------------- xs = (x @ W_gc) * rsqrt(deg+1) ----------------
__global__ __launch_bounds__(256) void k_xw_xs(const float* __restrict__ x, const float* __restrict__ Wgc,
                                               const int* __restrict__ deg,
                                               float* __restrict__ xs, int N) {
    __shared__ float Ws[NFEAT * H];
    for (int i = threadIdx.x; i < NFEAT * H; i += blockDim.x) Ws[i] = Wgc[i];
    __syncthreads();
    int n = blockIdx.x * blockDim.x + threadIdx.x;
    if (n >= N) return;
    float acc[H];
#pragma unroll
    for (int j = 0; j < H; j++) acc[j] = 0.f;
    const float4* x4 = (const float4*)(x + (size_t)n * NFEAT);
#pragma unroll 4
    for (int k4 = 0; k4 < NFEAT / 4; k4++) {
        float4 xv = x4[k4];
#pragma unroll
        for (int s = 0; s < 4; s++) {
            float xk = (s == 0) ? xv.x : (s == 1) ? xv.y : (s == 2) ? xv.z : xv.w;
            const float4* wrow = (const float4*)(Ws + (k4 * 4 + s) * H);
#pragma unroll
            for (int q = 0; q < 5; q++) {
                float4 w = wrow[q];
                acc[q * 4 + 0] += xk * w.x;
                acc[q * 4 + 1] += xk * w.y;
                acc[q * 4 + 2] += xk * w.z;
                acc[q * 4 + 3] += xk * w.w;
            }
        }
    }
    float di = rsqrtf((float)(deg[n] + 1));
    float4* o = (float4*)(xs + (size_t)n * H);
#pragma unroll
    for (int q = 0; q < 5; q++)
        o[q] = make_float4(acc[q * 4 + 0] * di, acc[q * 4 + 1] * di, acc[q * 4 + 2] * di, acc[q * 4 + 3] * di);
}

// ---------------- gather (neighbor-parallel): 16 lanes per node, DPP reduce ----------------
// Also folds the node_id head-bias: the 16 lanes owning node nid compute
// bcat2[j] = b[j] + x1[nid] . W[40:60, j]  (block-invariant for the edge MLP).
template <typename IT>
__device__ __forceinline__ void gather_core16(const float* __restrict__ xs, const IT* __restrict__ idx,
                                              int beg, int end, int n, int sl, int degn,
                                              const float* __restrict__ bgc, unsigned short* __restrict__ x1b,
                                              int nid, const float* __restrict__ Wmu, const float* __restrict__ Wvar,
                                              const float* __restrict__ bmu, const float* __restrict__ bvar,
                                              float* __restrict__ bcat2) {
    float acc[H];
    if (sl == 0) {   // self-loop term counted once
        const float4* self = (const float4*)(xs + (size_t)n * H);
#pragma unroll
        for (int q = 0; q < 5; q++) {
            float4 v = self[q];
            acc[q * 4 + 0] = v.x; acc[q * 4 + 1] = v.y; acc[q * 4 + 2] = v.z; acc[q * 4 + 3] = v.w;
        }
    } else {
#pragma unroll
        for (int j = 0; j < H; j++) acc[j] = 0.f;
    }
#pragma unroll 2
    for (int i = beg + sl; i < end; i += 16) {
        int r = (int)__builtin_nontemporal_load(idx + i);   // touch-once: keep xs L2-resident
        const float4* p = (const float4*)(xs + (size_t)r * H);
#pragma unroll
        for (int q = 0; q < 5; q++) {
            float4 v = p[q];
            acc[q * 4 + 0] += v.x; acc[q * 4 + 1] += v.y; acc[q * 4 + 2] += v.z; acc[q * 4 + 3] += v.w;
        }
    }
#pragma unroll
    for (int j = 0; j < H; j++) acc[j] = sum16(acc[j]);    // all 16 lanes hold the totals
    float di = rsqrtf((float)(degn + 1));
    float x1f[H];
#pragma unroll
    for (int j = 0; j < H; j++) x1f[j] = fmaxf(di * acc[j] + bgc[j], 0.f);
    if (sl == 0) {
        unsigned o[10];
#pragma unroll
        for (int j = 0; j < 10; j++) o[j] = pk2(f2bf(x1f[2 * j]), f2bf(x1f[2 * j + 1]));
        unsigned* dst = (unsigned*)(x1b + (size_t)n * H);
        *(uint4*)dst = make_uint4(o[0], o[1], o[2], o[3]);
        *(uint4*)(dst + 4) = make_uint4(o[4], o[5], o[6], o[7]);
        *(uint2*)(dst + 8) = make_uint2(o[8], o[9]);
    }
    if (n == nid) {   // 16 lanes split the 40 bias dots (~60 MACs each)
#pragma unroll
        for (int base = 0; base < 48; base += 16) {
            int jj = base + sl;
            if (jj < 40) {
                bool ismu = jj < 20;
                int col = ismu ? jj : jj - 20;
                const float* W = ismu ? Wmu : Wvar;
                float s = ismu ? bmu[col] : bvar[col];
#pragma unroll
                for (int k = 0; k < H; k++) s += x1f[k] * W[(2 * H + k) * H + col];
                bcat2[jj] = s;
            }
        }
    }
}

__global__ __launch_bounds__(256) void k_gather_csr16(const float* __restrict__ xs, const unsigned short* __restrict__ srcs,
                                                      const int* __restrict__ offsets, const int* __restrict__ deg,
                                                      const float* __restrict__ bgc,
                                                      unsigned short* __restrict__ x1b,
                                                      const int* __restrict__ node_id,
                                                      const float* __restrict__ Wmu, const float* __restrict__ Wvar,
                                                      const float* __restrict__ bmu, const float* __restrict__ bvar,
                                                      float* __restrict__ bcat2, int N) {
    int wave = (blockIdx.x * 256 + threadIdx.x) >> 6;
    int lane = threadIdx.x & 63;
    int n = wave * 4 + (lane >> 4);
    if (n >= N) return;
    gather_core16(xs, srcs, offsets[n], offsets[n + 1], n, lane & 15, deg[n], bgc, x1b,
                  node_id[0], Wmu, Wvar, bmu, bvar, bcat2);
}

__global__ __launch_bounds__(256) void k_gather_csr(const float* __restrict__ xs, const int* __restrict__ srcs,
                                                    const int* __restrict__ offsets, const int* __restrict__ deg,
                                                    const float* __restrict__ bgc,
                                                    unsigned short* __restrict__ x1b,
                                                    const int* __restrict__ node_id,
                                                    const float* __restrict__ Wmu, const float* __restrict__ Wvar,
                                                    const float* __restrict__ bmu, const float* __restrict__ bvar,
                                                    float* __restrict__ bcat2, int N) {
    int wave = (blockIdx.x * 256 + threadIdx.x) >> 6;
    int lane = threadIdx.x & 63;
    int n = wave * 4 + (lane >> 4);
    if (n >= N) return;
    gather_core16(xs, srcs, offsets[n], offsets[n + 1], n, lane & 15, deg[n], bgc, x1b,
                  node_id[0], Wmu, Wvar, bmu, bvar, bcat2);
}

// ---------------- fused per-edge MLP via MFMA ----------------
// VALU diet vs prior round: __expf (v_exp_f32, 2 inst) replaces libm expf (~14 inst) x9;
// node_id embedding removed from staging (folded into bcat2 bias) -> 10 chunks not 15.
__global__ __launch_bounds__(256, 8) void k_mlp(
    const unsigned short* __restrict__ x1b, const int* __restrict__ rows, const int* __restrict__ cols,
    const float* __restrict__ noise_n, const float* __restrict__ noise_u,
    const unsigned short* __restrict__ Bh, const unsigned short* __restrict__ Bd1g,
    const float* __restrict__ bcat2, const float* __restrict__ b_d1,
    const float* __restrict__ W_d2, const float* __restrict__ b_d2,
    float* __restrict__ out, int E) {

    __shared__ __align__(16) unsigned short x2s[BE * 72];     // 9216 B, rows 144 B (128 used)
    __shared__ __align__(16) unsigned short A2[BE * 44];      // 5632 B, rows 88 B (feats 0..31 valid)

    int tid = threadIdx.x;
    int e0 = blockIdx.x * BE;
    int l = tid & 63, w = tid >> 6;
    int m = l & 15, quad = l >> 4;
    int erow0 = w * 16 + quad * 4;

    // ---- prefetch z-phase noise early (HBM latency overlaps staging + heads MFMA) ----
    float nz0[4], nz1[4];
#pragma unroll
    for (int r4 = 0; r4 < 4; r4++) {
        int e = e0 + erow0 + r4;
        int ec = (e < E) ? e : 0;
        nz0[r4] = noise_n[(size_t)ec * H + m];
        nz1[r4] = (m < 4) ? noise_n[(size_t)ec * H + 16 + m] : 0.f;
    }

    // ---- stage x2 rows (bf16): [x1b[r] | x1b[c] | 0pad], coalesced 8B per group-of-4 lanes ----
    {
        int le = tid >> 2, p = tid & 3;
        int e = e0 + le; if (e >= E) e = E - 1;
        int r = rows[e], c = cols[e];
#pragma unroll
        for (int ii = 0; ii < 4; ii++) {
            int i = p + ii * 4;                    // 8B chunk 0..15
            unsigned* dst = (unsigned*)((char*)x2s + le * 144 + i * 8);
            if (i < 10) {
                int node = (i < 5) ? r : c;
                int cc = (i < 5) ? i : i - 5;
                uint2 v = *(const uint2*)((const char*)x1b + (size_t)node * 40 + cc * 8);
                dst[0] = v.x;
                dst[1] = v.y;
            } else {
                dst[0] = 0u; dst[1] = 0u;
            }
        }
    }
    __syncthreads();

    // ---- heads: 4 N-tiles (mu|mu_hi|lv|lv_hi) x 2 K-steps; B-frags from global/L1 ----
    f32x4 accs[4];
    {
        const char* arow = (const char*)x2s + (w * 16 + m) * 144 + quad * 16;
        short8 a0 = *(const short8*)(arow);
        short8 a1 = *(const short8*)(arow + 64);
#pragma unroll
        for (int t4 = 0; t4 < 4; t4++) {
            f32x4 acc = {0.f, 0.f, 0.f, 0.f};
            short8 b0 = *(const short8*)(Bh + (t4 * 2 + 0) * 512 + l * 8);
            short8 b1 = *(const short8*)(Bh + (t4 * 2 + 1) * 512 + l * 8);
            acc = __builtin_amdgcn_mfma_f32_16x16x32_bf16(a0, b0, acc, 0, 0, 0);
            acc = __builtin_amdgcn_mfma_f32_16x16x32_bf16(a1, b1, acc, 0, 0, 0);
            accs[t4] = acc;
        }
    }

    // ---- z = mu + exp(lv)*noise (registers) -> ds_write_b16 into A-layout A2 (stride 88) ----
    {
        float bm0 = bcat2[m];
        float bv0 = bcat2[20 + m];
        float bm1 = (m < 4) ? bcat2[16 + m] : 0.f;
        float bv1 = (m < 4) ? bcat2[36 + m] : 0.f;
#pragma unroll
        for (int r4 = 0; r4 < 4; r4++) {
            float z0 = accs[0][r4] + bm0 + __expf(accs[2][r4] + bv0) * nz0[r4];
            *(unsigned short*)((char*)A2 + (erow0 + r4) * 88 + m * 2) = f2bf(z0);
            unsigned short z1v = 0;   // lanes m>=4 zero-fill feats 20..31
            if (m < 4) z1v = f2bf(accs[1][r4] + bm1 + __expf(accs[3][r4] + bv1) * nz1[r4]);
            *(unsigned short*)((char*)A2 + (erow0 + r4) * 88 + (16 + m) * 2) = z1v;
        }
    }
    __syncthreads();

    // ---- decoder: h = relu(z @ Wd1 + b), sw = relu(h . wd2 + b2), log-free gumbel gate ----
    {
        short8 a2 = *(const short8*)((const char*)A2 + (w * 16 + m) * 88 + quad * 16);
        float p0 = 0.f, p1 = 0.f, p2 = 0.f, p3 = 0.f;
#pragma unroll
        for (int t4 = 0; t4 < 4; t4++) {
            f32x4 acc = {0.f, 0.f, 0.f, 0.f};
            short8 bb = *(const short8*)(Bd1g + t4 * 512 + l * 8);
            acc = __builtin_amdgcn_mfma_f32_16x16x32_bf16(a2, bb, acc, 0, 0, 0);
            int col = t4 * 16 + m;
            float bias = b_d1[col], wo = W_d2[col];
            p0 += fmaxf(acc[0] + bias, 0.f) * wo;
            p1 += fmaxf(acc[1] + bias, 0.f) * wo;
            p2 += fmaxf(acc[2] + bias, 0.f) * wo;
            p3 += fmaxf(acc[3] + bias, 0.f) * wo;
        }
        p0 = sum16(p0); p1 = sum16(p1); p2 = sum16(p2); p3 = sum16(p3);
        if (m < 4) {
            float swv = (m == 0) ? p0 : (m == 1) ? p1 : (m == 2) ? p2 : p3;
            int leo = w * 16 + quad * 4 + m;
            int e = e0 + leo;
            if (e < E) {
                float sw = fmaxf(swv + b_d2[0], 0.f);
                float u = noise_u[e];
                float ev = 0.9999f - 0.9998f * u;
                // sigmoid(log(ev/(1-ev)) + sw) == ev / (ev + (1-ev)*exp(-sw))
                float t = __expf(-sw);
                out[e] = ev / (ev + (1.f - ev) * t);
            }
        }
    }
}

extern "C" void kernel_launch(void* const* d_in, const int* in_sizes, int n_in,
                              void* d_out, int out_size, void* d_ws, size_t ws_size,
                              hipStream_t stream) {
    const int N = in_sizes[0] / NFEAT;   // 50000
    const int E = in_sizes[1] / 2;       // 1600000

    const float* x       = (const float*)d_in[0];
    const int*   ei      = (const int*)d_in[1];
    const int*   rows    = ei;
    const int*   cols    = ei + E;
    const int*   node_id = (const int*)d_in[2];
    const float* noise_n = (const float*)d_in[3];
    const float* noise_u = (const float*)d_in[4];
    const float* Wgc  = (const float*)d_in[5];
    const float* bgc  = (const float*)d_in[6];
    const float* Wmu  = (const float*)d_in[7];
    const float* bmu  = (const float*)d_in[8];
    const float* Wvar = (const float*)d_in[9];
    const float* bvar = (const float*)d_in[10];
    const float* Wd1  = (const float*)d_in[11];
    const float* bd1  = (const float*)d_in[12];
    const float* Wd2  = (const float*)d_in[13];
    const float* bd2  = (const float*)d_in[14];
    float* out = (float*)d_out;

    const int B = 256;
    int gN  = (N + B - 1) / B;
    int gG  = (N + 15) / 16;            // gather: 16 nodes per block (4 waves x 4 nodes)
    int gE  = (E + B - 1) / B;
    int gM  = (E + BE - 1) / BE;
    int nBins = (N + 255) / 256;        // <= 256 for N <= 65536

    char* ws = (char*)d_ws;
    // main-path layout (256B-aligned regions)
    size_t o_deg     = 0;
    size_t o_off     = o_deg  + (((size_t)N * 4 + 255) & ~255ULL);
    size_t o_csum    = o_off  + (((size_t)(N + 1) * 4 + 255) & ~255ULL);
    size_t o_coff    = o_csum + 1024;
    size_t o_hist    = o_coff + 1024;
    size_t wstride   = (size_t)((N + 3) >> 2);
    size_t o_delta   = o_hist  + ((NB * wstride * 4 + 255) & ~255ULL);
    size_t o_srcs    = o_delta + (((size_t)NB * N + 255) & ~255ULL);
    size_t o_xs      = o_srcs  + (((size_t)E * 2 + 255) & ~255ULL);
    size_t o_x1b     = o_xs    + (((size_t)N * H * 4 + 255) & ~255ULL);
    size_t o_Bh      = o_x1b   + (((size_t)N * H * 2 + 255) & ~255ULL);
    size_t o_Bd1     = o_Bh    + 8192;
    size_t o_bcat2   = o_Bd1   + 4096;
    size_t need      = o_bcat2 + 256;

    bool main_path = (ws_size >= need) && (N <= 4 * HW) && (N < 65536) && (nBins <= 256);

    if (main_path) {
        int*   deg     = (int*)(ws + o_deg);
        int*   offsets = (int*)(ws + o_off);
        int*   csum    = (int*)(ws + o_csum);
        int*   coff    = (int*)(ws + o_coff);
        unsigned* hist = (unsigned*)(ws + o_hist);
        unsigned char* delta = (unsigned char*)(ws + o_delta);
        unsigned short* srcs = (unsigned short*)(ws + o_srcs);
        float* xs      = (float*)(ws + o_xs);
        unsigned short* x1b  = (unsigned short*)(ws + o_x1b);
        unsigned short* Bh   = (unsigned short*)(ws + o_Bh);
        unsigned short* Bd1  = (unsigned short*)(ws + o_Bd1);
        float* bcat2   = (float*)(ws + o_bcat2);

        k_prep<<<gN, B, 0, stream>>>(Wmu, Wvar, Wd1, Bh, Bd1, deg, csum, N);
        k_hist<<<NB, 512, 0, stream>>>(cols, hist, csum, E, N);
        k_scansmall<<<1, B, 0, stream>>>(csum, coff, nBins);
        k_bases<<<nBins, B, 0, stream>>>(hist, coff, delta, offsets, deg, N, E);
        k_xw_xs<<<gN, B, 0, stream>>>(x, Wgc, deg, xs, N);
        k_place<<<NB, 512, 0, stream>>>(rows, cols, offsets, delta, srcs, E, N);
        k_gather_csr16<<<gG, B, 0, stream>>>(xs, srcs, offsets, deg, bgc, x1b,
                                             node_id, Wmu, Wvar, bmu, bvar, bcat2, N);
        k_mlp<<<gM, B, 0, stream>>>(x1b, rows, cols, noise_n, noise_u,
                                    Bh, Bd1, bcat2, bd1, Wd2, bd2, out, E);
    } else {
        int*   deg     = (int*)ws;                         //   200,000 B
        int*   offsets = (int*)(ws + 200000);              //   200,016 B
        int*   cursor  = (int*)(ws + 400016);              //   200,000 B
        int*   srcs    = (int*)(ws + 600016);              // 6,400,000 B
        float* xs      = (float*)(ws + 7000016);           // 4,000,000 B
        unsigned short* x1b = (unsigned short*)(ws + 11000016);  // 2,000,000 B
        unsigned short* Bh  = (unsigned short*)(ws + 13000016);  //     8,192 B
        unsigned short* Bd1 = (unsigned short*)(ws + 13008208);  //     4,096 B
        float* bcat2   = (float*)(ws + 13012304);          //       256 B

        k_prep<<<gN, B, 0, stream>>>(Wmu, Wvar, Wd1, Bh, Bd1, deg, cursor, N);
        k_deg<<<gE, B, 0, stream>>>(cols, deg, E);
        k_scan<<<1, SCAN_T, 0, stream>>>(deg, offsets, cursor, N);
        k_bucket_csr<<<gE, B, 0, stream>>>(rows, cols, cursor, srcs, E);
        k_xw_xs<<<gN, B, 0, stream>>>(x, Wgc, deg, xs, N);
        k_gather_csr<<<gG, B, 0, stream>>>(xs, srcs, offsets, deg, bgc, x1b,
                                           node_id, Wmu, Wvar, bmu, bvar, bcat2, N);
        k_mlp<<<gM, B, 0, stream>>>(x1b, rows, cols, noise_n, noise_u,
                                    Bh, Bd1, bcat2, bd1, Wd2, bd2, out, E);
    }
}